// Round 1
// 2316.633 us; speedup vs baseline: 1.0003x; 1.0003x over previous
//
#include <hip/hip_runtime.h>
#include <hip/hip_fp16.h>

typedef _Float16 half8 __attribute__((ext_vector_type(8)));
typedef float f32x4 __attribute__((ext_vector_type(4)));

#define T_STEPS 1024
#define INC 128
#define HIDC 256
#define G3 768
#define NN 100000
#define KSPLIT 32
#define NCHUNK 3125   // NN / KSPLIT
#define XS_STRIDE 144 // 16 c-groups * 8 + skew(12) + hf(4): max offset 139 -> stride 144

// ---------------- Phase 1: partials[ks][t][c] = sum over n-chunk of H[n,t]*X[n,c]
// 256 blocks (1D, XCD-swizzled), 512 threads, tile 128t x 128c, thread-tile 4x8.
// v2: (a) XCD swizzle: blocks i%8==xcd get ks in [xcd*4, xcd*4+4) x all 8 t-tiles,
//     so the 8 t-tiles sharing an X chunk are co-resident on one XCD -> X comes
//     from L2 instead of 8x HBM re-read.
//     (b) software pipeline: prefetch next 16-row tile into regs right after the
//     staging barrier; raw s_barrier (no vmcnt(0) drain) -> HBM latency hidden
//     under the ~2400-cycle compute phase instead of exposed at the barrier.
__global__ __launch_bounds__(512) void k_phase1(const float* __restrict__ X,
                                                const float* __restrict__ Hm,
                                                float* __restrict__ part){
  const int bid = blockIdx.x;         // 0..255
  const int xcd = bid & 7;
  const int idx = bid >> 3;           // 0..31
  const int ks  = xcd * 4 + (idx & 3);
  const int tt  = idx >> 2;           // 0..7
  const int t0 = tt * 128;
  const int nbeg = ks * NCHUNK;
  const int nend = nbeg + NCHUNK;
  __shared__ float Hs[16][128];
  __shared__ float Xs[16 * XS_STRIDE];   // bank-skewed, stride 144
  const int tid = threadIdx.x;
  const int tx = tid & 15;            // c-group: c0 = tx*8
  const int ty = tid >> 4;            // 0..31 : t rows ty*4..+3
  const int sr = tid >> 5;            // staging row 0..15
  const int sc = tid & 31;            // staging float4 col
  const int xskew = tx * 8 + (tx >> 2) * 4;   // 2-way max bank aliasing

  float acc[4][8];
  #pragma unroll
  for (int r = 0; r < 4; r++)
    #pragma unroll
    for (int q = 0; q < 8; q++) acc[r][q] = 0.f;

  // prologue prefetch (iter 0)
  float4 hv = make_float4(0.f,0.f,0.f,0.f), xv = make_float4(0.f,0.f,0.f,0.f);
  {
    int n = nbeg + sr;
    if (n < nend){
      hv = *(const float4*)(Hm + (size_t)n * T_STEPS + t0 + sc * 4);
      xv = *(const float4*)(X  + (size_t)n * INC + sc * 4);
    }
  }

  for (int n0 = nbeg; n0 < nend; n0 += 16){
    // (A) all waves finished reading the previous tile (their reads completed
    // before their own FMA uses) -> safe to overwrite LDS. Raw barrier: no
    // vmcnt drain, prefetch loads stay in flight.
    __builtin_amdgcn_s_barrier();
    asm volatile("" ::: "memory");
    *(float4*)&Hs[sr][sc * 4] = hv;
    {
      int g = sc >> 1, hf = sc & 1;   // c-group, half
      *(float4*)&Xs[sr * XS_STRIDE + g * 8 + (g >> 2) * 4 + hf * 4] = xv;
    }
    asm volatile("s_waitcnt lgkmcnt(0)" ::: "memory");
    __builtin_amdgcn_s_barrier();     // (B) tile visible to all waves
    asm volatile("" ::: "memory");

    // issue next tile's loads NOW; ~2400 cycles of FMA below hides the latency
    {
      int nn = n0 + 16 + sr;
      hv = make_float4(0.f,0.f,0.f,0.f);
      xv = make_float4(0.f,0.f,0.f,0.f);
      if (nn < nend){
        hv = *(const float4*)(Hm + (size_t)nn * T_STEPS + t0 + sc * 4);
        xv = *(const float4*)(X  + (size_t)nn * INC + sc * 4);
      }
    }

    #pragma unroll
    for (int i = 0; i < 16; i++){
      float4 h4 = *(const float4*)&Hs[i][ty * 4];
      float4 x0 = *(const float4*)&Xs[i * XS_STRIDE + xskew];
      float4 x1 = *(const float4*)&Xs[i * XS_STRIDE + xskew + 4];
      float xr[8] = {x0.x,x0.y,x0.z,x0.w,x1.x,x1.y,x1.z,x1.w};
      float hr[4] = {h4.x,h4.y,h4.z,h4.w};
      #pragma unroll
      for (int r = 0; r < 4; r++)
        #pragma unroll
        for (int q = 0; q < 8; q++)
          acc[r][q] += hr[r] * xr[q];
    }
  }
  #pragma unroll
  for (int r = 0; r < 4; r++){
    size_t o = ((size_t)ks * T_STEPS + t0 + ty * 4 + r) * INC + tx * 8;
    *(float4*)&part[o]     = make_float4(acc[r][0], acc[r][1], acc[r][2], acc[r][3]);
    *(float4*)&part[o + 4] = make_float4(acc[r][4], acc[r][5], acc[r][6], acc[r][7]);
  }
}

// ---------------- reduce k-splits -> visit_emb[t][c]
__global__ __launch_bounds__(256) void k_reduce(const float* __restrict__ part,
                                                float* __restrict__ ve){
  int idx = blockIdx.x * 256 + threadIdx.x;   // grid 512 -> 131072 cells
  float s = 0.f;
  #pragma unroll
  for (int ks = 0; ks < KSPLIT; ks++) s += part[(size_t)ks * (T_STEPS * INC) + idx];
  ve[idx] = s;
}

// ---------------- gxq[t][unit][gate] = ve[t]·w_ih[row] + b_ih[row] (+ b_hh for r,z)
__global__ __launch_bounds__(768) void k_gx(const float* __restrict__ ve,
                                            const float* __restrict__ w_ih,
                                            const float* __restrict__ b_ih,
                                            const float* __restrict__ b_hh,
                                            float* __restrict__ gxq){
  const int t = blockIdx.x;
  const int j = threadIdx.x;          // row 0..767
  __shared__ float4 v4[32];
  if (j < 32) v4[j] = *(const float4*)(ve + (size_t)t * INC + j * 4);
  __syncthreads();
  const float4* wr = (const float4*)(w_ih + (size_t)j * INC);
  float a0 = 0.f, a1 = 0.f, a2 = 0.f, a3 = 0.f;
  #pragma unroll
  for (int q = 0; q < 32; q++){
    float4 w = wr[q]; float4 v = v4[q];
    a0 += w.x * v.x; a1 += w.y * v.y; a2 += w.z * v.z; a3 += w.w * v.w;
  }
  float bias = b_ih[j] + (j < 512 ? b_hh[j] : 0.f);
  gxq[(size_t)t * 1024 + (j & 255) * 4 + (j >> 8)] = (a0 + a1) + (a2 + a3) + bias;
}

// ---------------- GRU scan: 1 block, 1024 threads = 16 waves, MFMA GEMV.
// Wave w owns units [16w,16w+16): computes r,z,n gate rows for those units.
// A trick: all 16 A-rows = h (lane reads h[quad*8+j]) -> every D reg holds
// dot(h, w_hh[gate*256 + (lane&15) + 16w]). One barrier/step, double-buffered h.
// v2: raw s_barrier + lgkmcnt(0) only. __syncthreads drained vmcnt(0) each step,
// serializing on the gxq prefetch load + hs store-ack (~1000 cyc/step exposed).
// Only the hbuf ds_write needs completion before the barrier; gxq/hs global ops
// stay in flight across it (their uses are a full step away -> latency hidden).
__global__ __launch_bounds__(1024) void k_gru(const float* __restrict__ w_hh,
                                              const float* __restrict__ b_hh,
                                              const float* __restrict__ gxq,
                                              float* __restrict__ hs){
  const int tid  = threadIdx.x;
  const int w    = tid >> 6;
  const int l    = tid & 63;
  const int col  = l & 15;
  const int quad = l >> 4;
  const int unit = w * 16 + col;      // 0..255

  __shared__ _Float16 hbuf[2][256];

  // B fragments, register-resident fp16: [gate][k-chunk], 96 VGPRs
  half8 Bf[3][8];
  #pragma unroll
  for (int g = 0; g < 3; g++){
    const float* wr = w_hh + (size_t)(g * 256 + unit) * HIDC + quad * 8;
    #pragma unroll
    for (int c = 0; c < 8; c++){
      float4 v0 = *(const float4*)(wr + c * 32);
      float4 v1 = *(const float4*)(wr + c * 32 + 4);
      half8 b;
      b[0]=(_Float16)v0.x; b[1]=(_Float16)v0.y; b[2]=(_Float16)v0.z; b[3]=(_Float16)v0.w;
      b[4]=(_Float16)v1.x; b[5]=(_Float16)v1.y; b[6]=(_Float16)v1.z; b[7]=(_Float16)v1.w;
      Bf[g][c] = b;
    }
  }
  const float bn = b_hh[512 + unit];
  float hprev = 0.f;
  if (tid < 256) hbuf[0][tid] = (_Float16)0.f;
  __syncthreads();

  f32x4 gq = *(const f32x4*)(gxq + (size_t)unit * 4);   // t=0

  for (int t = 0; t < T_STEPS; t++){
    f32x4 dr = {0.f,0.f,0.f,0.f}, dz = {0.f,0.f,0.f,0.f}, dn = {0.f,0.f,0.f,0.f};
    const _Float16* hb = hbuf[t & 1];
    #pragma unroll
    for (int c = 0; c < 8; c++){
      half8 a = *(const half8*)(hb + c * 32 + quad * 8);
      dr = __builtin_amdgcn_mfma_f32_16x16x32_f16(a, Bf[0][c], dr, 0, 0, 0);
      dz = __builtin_amdgcn_mfma_f32_16x16x32_f16(a, Bf[1][c], dz, 0, 0, 0);
      dn = __builtin_amdgcn_mfma_f32_16x16x32_f16(a, Bf[2][c], dn, 0, 0, 0);
    }
    // prefetch next step's gx (pad row at t=1023); stays in flight across the
    // raw barrier, vmcnt waited only at next step's use.
    f32x4 gq_n = *(const f32x4*)(gxq + (size_t)(t + 1) * 1024 + unit * 4);

    float r = 1.f / (1.f + __expf(-(gq[0] + dr[0])));
    float z = 1.f / (1.f + __expf(-(gq[1] + dz[0])));
    float pre = gq[2] + r * (dn[0] + bn);
    float ax = fabsf(pre);
    float e = __expf(-2.f * ax);
    float th = (1.f - e) / (1.f + e);
    float n = copysignf(th, pre);
    float hnew = n + z * (hprev - n);
    hprev = hnew;
    if (quad == 0){
      hbuf[(t + 1) & 1][unit] = (_Float16)hnew;
      hs[(size_t)t * HIDC + unit] = hnew;
    }
    // hbuf write visible to all waves; do NOT drain vmcnt (gxq load / hs store
    // keep flowing). Reads of hbuf[t&1] this step completed before our MFMAs,
    // hence before this wait -> next step's overwrite is safe.
    asm volatile("s_waitcnt lgkmcnt(0)" ::: "memory");
    __builtin_amdgcn_s_barrier();
    asm volatile("" ::: "memory");
    gq = gq_n;
  }
}

// ---------------- logits[t] = hs[t]·w_attn
__global__ __launch_bounds__(64) void k_logits(const float* __restrict__ hs,
                                               const float* __restrict__ w_attn,
                                               float* __restrict__ logits){
  int t = blockIdx.x;
  int l = threadIdx.x;
  float4 hv = *(const float4*)(hs + (size_t)t * HIDC + l * 4);
  float4 wv = *(const float4*)(w_attn + l * 4);
  float p = hv.x * wv.x + hv.y * wv.y + hv.z * wv.z + hv.w * wv.w;
  #pragma unroll
  for (int o = 32; o > 0; o >>= 1) p += __shfl_down(p, o);
  if (l == 0) logits[t] = p;
}

// ---------------- softmax + weighted sum -> out[256]
__global__ __launch_bounds__(1024) void k_attn(const float* __restrict__ logits,
                                               const float* __restrict__ hs,
                                               float* __restrict__ out){
  __shared__ float sm[1024];
  __shared__ float al[1024];
  __shared__ float ps[4][HIDC];
  int tid = threadIdx.x;
  float lg = logits[tid];
  sm[tid] = lg; __syncthreads();
  for (int s = 512; s > 0; s >>= 1){
    if (tid < s) sm[tid] = fmaxf(sm[tid], sm[tid + s]);
    __syncthreads();
  }
  float mx = sm[0]; __syncthreads();
  float e = __expf(lg - mx);
  sm[tid] = e; __syncthreads();
  for (int s = 512; s > 0; s >>= 1){
    if (tid < s) sm[tid] += sm[tid + s];
    __syncthreads();
  }
  float inv = 1.f / sm[0];
  al[tid] = e * inv;
  __syncthreads();
  int c = tid & 255; int tq = tid >> 8;
  float acc = 0.f;
  for (int t = tq; t < T_STEPS; t += 4) acc += al[t] * hs[(size_t)t * HIDC + c];
  ps[tq][c] = acc; __syncthreads();
  if (tid < HIDC) out[tid] = (ps[0][tid] + ps[1][tid]) + (ps[2][tid] + ps[3][tid]);
}

extern "C" void kernel_launch(void* const* d_in, const int* in_sizes, int n_in,
                              void* d_out, int out_size, void* d_ws, size_t ws_size,
                              hipStream_t stream){
  const float* X      = (const float*)d_in[0];
  const float* Hm     = (const float*)d_in[1];
  const float* w_ih   = (const float*)d_in[2];
  const float* w_hh   = (const float*)d_in[3];
  const float* b_ih   = (const float*)d_in[4];
  const float* b_hh   = (const float*)d_in[5];
  const float* w_attn = (const float*)d_in[6];
  float* out = (float*)d_out;

  float* ws     = (float*)d_ws;
  float* part   = ws;                       // 32*1024*128 = 4,194,304 f
  float* ve     = part + 4194304;           // 131,072 f
  float* gxq    = ve + 131072;              // 1024*1024 + 1024 pad = 1,049,600 f
  float* hs     = gxq + 1049600;            // 262,144 f
  float* logits = hs + 262144;              // 1,024 f   (~22.6 MB total)

  k_phase1<<<256, 512, 0, stream>>>(X, Hm, part);
  k_reduce<<<512, 256, 0, stream>>>(part, ve);
  k_gx<<<1024, 768, 0, stream>>>(ve, w_ih, b_ih, b_hh, gxq);
  k_gru<<<1, 1024, 0, stream>>>(w_hh, b_hh, gxq, hs);
  k_logits<<<1024, 64, 0, stream>>>(hs, w_attn, logits);
  k_attn<<<1, 1024, 0, stream>>>(logits, hs, out);
}

// Round 2
// 2195.557 us; speedup vs baseline: 1.0554x; 1.0551x over previous
//
#include <hip/hip_runtime.h>
#include <hip/hip_fp16.h>

typedef _Float16 half8 __attribute__((ext_vector_type(8)));
typedef _Float16 half2v __attribute__((ext_vector_type(2)));
typedef float f32x4 __attribute__((ext_vector_type(4)));

#define T_STEPS 1024
#define INC 128
#define HIDC 256
#define G3 768
#define NN 100000
#define KSPLIT 32
#define NCHUNK 3125   // NN / KSPLIT
#define XS_STRIDE 144 // 16 c-groups * 8 + skew(12) + hf(4): max offset 139 -> stride 144

// quad_perm [1,0,3,2] : xor-1 within each quad, pure-VALU lane exchange
__device__ __forceinline__ float dpp_xor1(float v){
  int t = __builtin_amdgcn_update_dpp(0, __float_as_int(v), 0xB1, 0xF, 0xF, true);
  return __int_as_float(t);
}

// ---------------- Phase 1: partials[ks][t][c] = sum over n-chunk of H[n,t]*X[n,c]
// 256 blocks (1D, XCD-swizzled), 512 threads, tile 128t x 128c, thread-tile 4x8.
__global__ __launch_bounds__(512) void k_phase1(const float* __restrict__ X,
                                                const float* __restrict__ Hm,
                                                float* __restrict__ part){
  const int bid = blockIdx.x;         // 0..255
  const int xcd = bid & 7;
  const int idx = bid >> 3;           // 0..31
  const int ks  = xcd * 4 + (idx & 3);
  const int tt  = idx >> 2;           // 0..7
  const int t0 = tt * 128;
  const int nbeg = ks * NCHUNK;
  const int nend = nbeg + NCHUNK;
  __shared__ float Hs[16][128];
  __shared__ float Xs[16 * XS_STRIDE];   // bank-skewed, stride 144
  const int tid = threadIdx.x;
  const int tx = tid & 15;            // c-group: c0 = tx*8
  const int ty = tid >> 4;            // 0..31 : t rows ty*4..+3
  const int sr = tid >> 5;            // staging row 0..15
  const int sc = tid & 31;            // staging float4 col
  const int xskew = tx * 8 + (tx >> 2) * 4;   // 2-way max bank aliasing

  float acc[4][8];
  #pragma unroll
  for (int r = 0; r < 4; r++)
    #pragma unroll
    for (int q = 0; q < 8; q++) acc[r][q] = 0.f;

  // prologue prefetch (iter 0)
  float4 hv = make_float4(0.f,0.f,0.f,0.f), xv = make_float4(0.f,0.f,0.f,0.f);
  {
    int n = nbeg + sr;
    if (n < nend){
      hv = *(const float4*)(Hm + (size_t)n * T_STEPS + t0 + sc * 4);
      xv = *(const float4*)(X  + (size_t)n * INC + sc * 4);
    }
  }

  for (int n0 = nbeg; n0 < nend; n0 += 16){
    __builtin_amdgcn_s_barrier();     // prev tile's readers done (their own lgkm drained)
    asm volatile("" ::: "memory");
    *(float4*)&Hs[sr][sc * 4] = hv;
    {
      int g = sc >> 1, hf = sc & 1;   // c-group, half
      *(float4*)&Xs[sr * XS_STRIDE + g * 8 + (g >> 2) * 4 + hf * 4] = xv;
    }
    asm volatile("s_waitcnt lgkmcnt(0)" ::: "memory");
    __builtin_amdgcn_s_barrier();     // tile visible to all waves
    asm volatile("" ::: "memory");

    // issue next tile's loads NOW; FMA phase below hides HBM latency
    {
      int nn = n0 + 16 + sr;
      hv = make_float4(0.f,0.f,0.f,0.f);
      xv = make_float4(0.f,0.f,0.f,0.f);
      if (nn < nend){
        hv = *(const float4*)(Hm + (size_t)nn * T_STEPS + t0 + sc * 4);
        xv = *(const float4*)(X  + (size_t)nn * INC + sc * 4);
      }
    }

    #pragma unroll
    for (int i = 0; i < 16; i++){
      float4 h4 = *(const float4*)&Hs[i][ty * 4];
      float4 x0 = *(const float4*)&Xs[i * XS_STRIDE + xskew];
      float4 x1 = *(const float4*)&Xs[i * XS_STRIDE + xskew + 4];
      float xr[8] = {x0.x,x0.y,x0.z,x0.w,x1.x,x1.y,x1.z,x1.w};
      float hr[4] = {h4.x,h4.y,h4.z,h4.w};
      #pragma unroll
      for (int r = 0; r < 4; r++)
        #pragma unroll
        for (int q = 0; q < 8; q++)
          acc[r][q] += hr[r] * xr[q];
    }
  }
  #pragma unroll
  for (int r = 0; r < 4; r++){
    size_t o = ((size_t)ks * T_STEPS + t0 + ty * 4 + r) * INC + tx * 8;
    *(float4*)&part[o]     = make_float4(acc[r][0], acc[r][1], acc[r][2], acc[r][3]);
    *(float4*)&part[o + 4] = make_float4(acc[r][4], acc[r][5], acc[r][6], acc[r][7]);
  }
}

// ---------------- reduce k-splits -> visit_emb[t][c]
__global__ __launch_bounds__(256) void k_reduce(const float* __restrict__ part,
                                                float* __restrict__ ve){
  int idx = blockIdx.x * 256 + threadIdx.x;   // grid 512 -> 131072 cells
  float s = 0.f;
  #pragma unroll
  for (int ks = 0; ks < KSPLIT; ks++) s += part[(size_t)ks * (T_STEPS * INC) + idx];
  ve[idx] = s;
}

// ---------------- gxq[t][unit][gate] = ve[t]·w_ih[row] + b_ih[row] (+ b_hh for r,z)
__global__ __launch_bounds__(768) void k_gx(const float* __restrict__ ve,
                                            const float* __restrict__ w_ih,
                                            const float* __restrict__ b_ih,
                                            const float* __restrict__ b_hh,
                                            float* __restrict__ gxq){
  const int t = blockIdx.x;
  const int j = threadIdx.x;          // row 0..767
  __shared__ float4 v4[32];
  if (j < 32) v4[j] = *(const float4*)(ve + (size_t)t * INC + j * 4);
  __syncthreads();
  const float4* wr = (const float4*)(w_ih + (size_t)j * INC);
  float a0 = 0.f, a1 = 0.f, a2 = 0.f, a3 = 0.f;
  #pragma unroll
  for (int q = 0; q < 32; q++){
    float4 w = wr[q]; float4 v = v4[q];
    a0 += w.x * v.x; a1 += w.y * v.y; a2 += w.z * v.z; a3 += w.w * v.w;
  }
  float bias = b_ih[j] + (j < 512 ? b_hh[j] : 0.f);
  gxq[(size_t)t * 1024 + (j & 255) * 4 + (j >> 8)] = (a0 + a1) + (a2 + a3) + bias;
}

// ---------------- GRU scan v3: 512 threads (8 waves, 2/SIMD -> 256-reg budget).
// Lane layout: unit = tid>>1 (0..255), ks = tid&1 (k-half of 128).
// Weights w_hh live ENTIRELY in registers as fp16: 3 gates x 64 half2 = 192 VGPRs
// (the 1024-thread MFMA version was capped at 128 regs/lane -> Bf spilled to
// scratch and was reloaded every step; VGPR_Count=64 in rocprof was the tell).
// GEMV via v_dot2_f32_f16 (fp16 mul, fp32 acc - same numerics as the MFMA path):
// 192 fdot2/lane/step, issue floor ~1000 cyc/SIMD/step vs MFMA's 1863 + spills.
// k-half reduce = one quad_perm DPP xor-1 (no LDS, no divergence).
__global__ __launch_bounds__(512, 2) void k_gru(const float* __restrict__ w_hh,
                                                const float* __restrict__ b_hh,
                                                const float* __restrict__ gxq,
                                                float* __restrict__ hs){
  const int tid  = threadIdx.x;
  const int unit = tid >> 1;          // 0..255
  const int ks   = tid & 1;           // k-half
  const int k0   = ks * 128;

  __shared__ _Float16 hbuf[2][256];

  // register-resident fp16 weights: Bp[gate][64 half2] = 192 VGPRs
  half2v Bp[3][64];
  #pragma unroll
  for (int g = 0; g < 3; g++){
    const float* wr = w_hh + (size_t)(g * 256 + unit) * HIDC + k0;
    #pragma unroll
    for (int c = 0; c < 32; c++){
      float4 v = *(const float4*)(wr + c * 4);
      half2v p0; p0[0] = (_Float16)v.x; p0[1] = (_Float16)v.y;
      half2v p1; p1[0] = (_Float16)v.z; p1[1] = (_Float16)v.w;
      Bp[g][2 * c]     = p0;
      Bp[g][2 * c + 1] = p1;
    }
  }
  const float bn = b_hh[512 + unit];
  float hprev = 0.f;
  if (tid < 256) hbuf[0][tid] = (_Float16)0.f;
  __syncthreads();

  f32x4 gq = *(const f32x4*)(gxq + (size_t)unit * 4);   // t=0

  for (int t = 0; t < T_STEPS; t++){
    const _Float16* hb = &hbuf[t & 1][k0];
    float ar0 = 0.f, ar1 = 0.f, az0 = 0.f, az1 = 0.f, an0 = 0.f, an1 = 0.f;
    #pragma unroll
    for (int c = 0; c < 16; c++){
      half8 hv = *(const half8*)(hb + c * 8);   // 16B, 2 unique addrs/wave: 2-way (free)
      #pragma unroll
      for (int q = 0; q < 4; q++){
        half2v hp; hp[0] = hv[2 * q]; hp[1] = hv[2 * q + 1];
        if (c & 1){
          ar1 = __builtin_amdgcn_fdot2(hp, Bp[0][4 * c + q], ar1, false);
          az1 = __builtin_amdgcn_fdot2(hp, Bp[1][4 * c + q], az1, false);
          an1 = __builtin_amdgcn_fdot2(hp, Bp[2][4 * c + q], an1, false);
        } else {
          ar0 = __builtin_amdgcn_fdot2(hp, Bp[0][4 * c + q], ar0, false);
          az0 = __builtin_amdgcn_fdot2(hp, Bp[1][4 * c + q], az0, false);
          an0 = __builtin_amdgcn_fdot2(hp, Bp[2][4 * c + q], an0, false);
        }
      }
    }
    // prefetch next step's gx (pad row exists at t=1023)
    f32x4 gq_n = *(const f32x4*)(gxq + (size_t)(t + 1) * 1024 + unit * 4);

    float dr = ar0 + ar1; dr += dpp_xor1(dr);   // + other k-half
    float dz = az0 + az1; dz += dpp_xor1(dz);
    float dn = an0 + an1; dn += dpp_xor1(dn);

    float r = 1.f / (1.f + __expf(-(gq[0] + dr)));
    float z = 1.f / (1.f + __expf(-(gq[1] + dz)));
    float pre = gq[2] + r * (dn + bn);
    float ax = fabsf(pre);
    float e = __expf(-2.f * ax);
    float th = (1.f - e) / (1.f + e);
    float n = copysignf(th, pre);
    float hnew = n + z * (hprev - n);
    hprev = hnew;
    if (ks == 0){
      hbuf[(t + 1) & 1][unit] = (_Float16)hnew;
      hs[(size_t)t * HIDC + unit] = hnew;
    }
    gq = gq_n;
    __syncthreads();
  }
}

// ---------------- logits[t] = hs[t]·w_attn
__global__ __launch_bounds__(64) void k_logits(const float* __restrict__ hs,
                                               const float* __restrict__ w_attn,
                                               float* __restrict__ logits){
  int t = blockIdx.x;
  int l = threadIdx.x;
  float4 hv = *(const float4*)(hs + (size_t)t * HIDC + l * 4);
  float4 wv = *(const float4*)(w_attn + l * 4);
  float p = hv.x * wv.x + hv.y * wv.y + hv.z * wv.z + hv.w * wv.w;
  #pragma unroll
  for (int o = 32; o > 0; o >>= 1) p += __shfl_down(p, o);
  if (l == 0) logits[t] = p;
}

// ---------------- softmax + weighted sum -> out[256]
__global__ __launch_bounds__(1024) void k_attn(const float* __restrict__ logits,
                                               const float* __restrict__ hs,
                                               float* __restrict__ out){
  __shared__ float sm[1024];
  __shared__ float al[1024];
  __shared__ float ps[4][HIDC];
  int tid = threadIdx.x;
  float lg = logits[tid];
  sm[tid] = lg; __syncthreads();
  for (int s = 512; s > 0; s >>= 1){
    if (tid < s) sm[tid] = fmaxf(sm[tid], sm[tid + s]);
    __syncthreads();
  }
  float mx = sm[0]; __syncthreads();
  float e = __expf(lg - mx);
  sm[tid] = e; __syncthreads();
  for (int s = 512; s > 0; s >>= 1){
    if (tid < s) sm[tid] += sm[tid + s];
    __syncthreads();
  }
  float inv = 1.f / sm[0];
  al[tid] = e * inv;
  __syncthreads();
  int c = tid & 255; int tq = tid >> 8;
  float acc = 0.f;
  for (int t = tq; t < T_STEPS; t += 4) acc += al[t] * hs[(size_t)t * HIDC + c];
  ps[tq][c] = acc; __syncthreads();
  if (tid < HIDC) out[tid] = (ps[0][tid] + ps[1][tid]) + (ps[2][tid] + ps[3][tid]);
}

extern "C" void kernel_launch(void* const* d_in, const int* in_sizes, int n_in,
                              void* d_out, int out_size, void* d_ws, size_t ws_size,
                              hipStream_t stream){
  const float* X      = (const float*)d_in[0];
  const float* Hm     = (const float*)d_in[1];
  const float* w_ih   = (const float*)d_in[2];
  const float* w_hh   = (const float*)d_in[3];
  const float* b_ih   = (const float*)d_in[4];
  const float* b_hh   = (const float*)d_in[5];
  const float* w_attn = (const float*)d_in[6];
  float* out = (float*)d_out;

  float* ws     = (float*)d_ws;
  float* part   = ws;                       // 32*1024*128 = 4,194,304 f
  float* ve     = part + 4194304;           // 131,072 f
  float* gxq    = ve + 131072;              // 1024*1024 + 1024 pad = 1,049,600 f
  float* hs     = gxq + 1049600;            // 262,144 f
  float* logits = hs + 262144;              // 1,024 f   (~22.6 MB total)

  k_phase1<<<256, 512, 0, stream>>>(X, Hm, part);
  k_reduce<<<512, 256, 0, stream>>>(part, ve);
  k_gx<<<1024, 768, 0, stream>>>(ve, w_ih, b_ih, b_hh, gxq);
  k_gru<<<1, 512, 0, stream>>>(w_hh, b_hh, gxq, hs);
  k_logits<<<1024, 64, 0, stream>>>(hs, w_attn, logits);
  k_attn<<<1, 1024, 0, stream>>>(logits, hs, out);
}